// Round 12
// baseline (233.175 us; speedup 1.0000x reference)
//
#include <hip/hip_runtime.h>

#define B_   8
#define C_   256
#define TC_  512
#define HW_  2304   // 48*48
#define EPS_ 1e-6f

typedef __bf16 bf16_t;
typedef __bf16 bf16x8 __attribute__((ext_vector_type(8)));
typedef float  f32x4 __attribute__((ext_vector_type(4)));
typedef unsigned int  u32;
typedef long long     i64;
typedef unsigned char u8;

// async 16B global->LDS; lds dest is wave-uniform base (lane i -> base+16i)
__device__ __forceinline__ void g2l16(const void* g, void* l) {
    __builtin_amdgcn_global_load_lds(
        (const __attribute__((address_space(1))) unsigned int*)g,
        (__attribute__((address_space(3))) unsigned int*)l, 16, 0, 0);
}

__device__ __forceinline__ u8 to_fp8(float v) {
    return (u8)(__builtin_amdgcn_cvt_pk_fp8_f32(v, v, 0, false) & 0xff);
}

// ---------------------------------------------------------------------------
// W -> fragment-major bf16 (unchanged).
// ---------------------------------------------------------------------------
__global__ __launch_bounds__(256)
void wfrag_kernel(const float* __restrict__ wq, const float* __restrict__ wk,
                  const float* __restrict__ wv,
                  bf16_t* __restrict__ oq, bf16_t* __restrict__ ok,
                  bf16_t* __restrict__ ov)
{
    const int fid = blockIdx.x * 4 + (threadIdx.x >> 6);   // 0..639
    const int lane = threadIdx.x & 63;
    const int l16 = lane & 15, quad = lane >> 4;

    const float* src; bf16_t* dst; int cin, f;
    if (fid < 128)      { src = wq; dst = oq; cin = C_;  f = fid; }
    else if (fid < 384) { src = wk; dst = ok; cin = TC_; f = fid - 128; }
    else                { src = wv; dst = ov; cin = TC_; f = fid - 384; }
    const int nks = cin / 32;
    const int ot = f / nks, ks = f % nks;

    const float* s = src + (size_t)(ot * 16 + l16) * cin + ks * 32 + quad * 8;
    float4 a = *(const float4*)(s);
    float4 b = *(const float4*)(s + 4);
    bf16x8 o;
    o[0] = (__bf16)a.x; o[1] = (__bf16)a.y; o[2] = (__bf16)a.z; o[3] = (__bf16)a.w;
    o[4] = (__bf16)b.x; o[5] = (__bf16)b.y; o[6] = (__bf16)b.z; o[7] = (__bf16)b.w;
    *(bf16x8*)(dst + (size_t)f * 512 + lane * 8) = o;
}

// ---------------------------------------------------------------------------
// ROUND 12: conv1+conv2 MERGED into one launch (grid 2304; block branch).
// Body = the PROVEN r7/r10 16-px structure (store packing r9/r10 neutral,
// 64-px r11 regressed -> reverted).  Purpose: (a) one less launch gap,
// (b) the merged kernel is finally VISIBLE in the top-5 profile with its
// own counters -- the conv cost has only ever been inferred by subtraction.
//   KFMT=0: q8  [b][n][C]
//   KFMT=1: k8' [b][cchunk=o/8][j=n][8 bytes]
//   DO_V :  v8' [b][jchunk=n/8][c=o][8 bytes]
// ---------------------------------------------------------------------------
template<int CIN, bool DO_V, bool KFMT>
__device__ __forceinline__ void conv_body(const float* __restrict__ X,
                                          const bf16_t* __restrict__ Wa,
                                          const bf16_t* __restrict__ Wvp,
                                          u8* __restrict__ outA, u8* __restrict__ outV,
                                          int bid, u8* smem)
{
    const int b  = bid & 7;
    const int n0 = (bid >> 3) * 16;
    const int tid = threadIdx.x;
    const int wv = tid >> 6;
    const int lane = tid & 63;
    const int quad = lane >> 4, l16 = lane & 15;
    const int NKS = CIN / 32;

    bf16_t (*T)[CIN + 8] = (bf16_t (*)[CIN + 8])smem;
    float (*ssp)[16] = (float (*)[16])(smem + (size_t)16 * (CIN + 8) * 2);

    // ---- stage: fp32 [c][n] -> bf16 T[n][c] ----
    {
        const float* Xb = X + (size_t)b * CIN * HW_ + n0;
        const int cl = tid >> 2;          // 0..63
        const int n4 = (tid & 3) * 4;     // 0,4,8,12
#pragma unroll
        for (int cp = 0; cp < CIN; cp += 64) {
            float4 v = *(const float4*)(Xb + (size_t)(cp + cl) * HW_ + n4);
            T[n4 + 0][cp + cl] = (__bf16)v.x;
            T[n4 + 1][cp + cl] = (__bf16)v.y;
            T[n4 + 2][cp + cl] = (__bf16)v.z;
            T[n4 + 3][cp + cl] = (__bf16)v.w;
        }
    }
    __syncthreads();

    // ---- all 16 px rows into registers ----
    bf16x8 af[CIN / 32];
#pragma unroll
    for (int ks = 0; ks < CIN / 32; ks++)
        af[ks] = *(const bf16x8*)(&T[l16][ks * 32 + quad * 8]);

    const int ot0 = wv * 4;

    // ---- K-GEMM ----
    f32x4 accK[4];
#pragma unroll
    for (int p = 0; p < 4; p++) accK[p] = (f32x4){0.f, 0.f, 0.f, 0.f};
    {
        const bf16_t* wbase = Wa + ((size_t)ot0 * NKS) * 512 + lane * 8;
#pragma unroll
        for (int ks = 0; ks < CIN / 32; ks++)
#pragma unroll
            for (int p = 0; p < 4; p++) {
                bf16x8 bw = *(const bf16x8*)(wbase + (size_t)(p * NKS + ks) * 512);
                accK[p] = __builtin_amdgcn_mfma_f32_16x16x32_bf16(af[ks], bw, accK[p], 0, 0, 0);
            }
    }

    // ---- per-wave partial sum of squares over this wave's 64 o ----
    {
        float ssr[4];
#pragma unroll
        for (int r = 0; r < 4; r++) {
            float ss = accK[0][r] * accK[0][r] + accK[1][r] * accK[1][r]
                     + accK[2][r] * accK[2][r] + accK[3][r] * accK[3][r];
            ss += __shfl_xor(ss, 1);
            ss += __shfl_xor(ss, 2);
            ss += __shfl_xor(ss, 4);
            ss += __shfl_xor(ss, 8);
            ssr[r] = ss;
        }
        if (l16 == 0) {
#pragma unroll
            for (int r = 0; r < 4; r++) ssp[wv][quad * 4 + r] = ssr[r];
        }
    }

    // ---- V-GEMM (hides the ssp barrier) ----
    f32x4 accV[4];
    if (DO_V) {
#pragma unroll
        for (int p = 0; p < 4; p++) accV[p] = (f32x4){0.f, 0.f, 0.f, 0.f};
        const bf16_t* wbase = Wvp + ((size_t)ot0 * NKS) * 512 + lane * 8;
#pragma unroll
        for (int ks = 0; ks < CIN / 32; ks++)
#pragma unroll
            for (int p = 0; p < 4; p++) {
                bf16x8 aw = *(const bf16x8*)(wbase + (size_t)(p * NKS + ks) * 512);
                accV[p] = __builtin_amdgcn_mfma_f32_16x16x32_bf16(aw, af[ks], accV[p], 0, 0, 0);
            }
    }

    __syncthreads();

    // ---- combine norm partials, scale, write fp8 q/k ----
    float scale[4];
#pragma unroll
    for (int r = 0; r < 4; r++) {
        int px = quad * 4 + r;
        float s = ssp[0][px] + ssp[1][px] + ssp[2][px] + ssp[3][px];
        scale[r] = 1.0f / fmaxf(sqrtf(s), EPS_);
    }
    if (!KFMT) {
        // q8 [b][n][C]: row = px = quad*4+r, col = o = (ot0+p)*16 + l16
        u8* oa = outA + ((size_t)b * HW_ + n0 + quad * 4) * C_ + l16;
#pragma unroll
        for (int p = 0; p < 4; p++)
#pragma unroll
            for (int r = 0; r < 4; r++)
                oa[(size_t)r * C_ + (ot0 + p) * 16] = to_fp8(accK[p][r] * scale[r]);
    } else {
        // k8' [b][cc][j][8]: cc = o>>3 = (ot0+p)*2 + (l16>>3), byte = l16&7
        u8* oa = outA + (size_t)b * 32 * HW_ * 8;
#pragma unroll
        for (int p = 0; p < 4; p++)
#pragma unroll
            for (int r = 0; r < 4; r++)
                oa[(((size_t)((ot0 + p) * 2 + (l16 >> 3))) * HW_
                    + n0 + quad * 4 + r) * 8 + (l16 & 7)]
                    = to_fp8(accK[p][r] * scale[r]);
    }

    if (DO_V) {
        // v8' [b][jc][c][8]: jc = (n0+l16)>>3, c = o = (ot0+p)*16+quad*4+r
#pragma unroll
        for (int p = 0; p < 4; p++)
#pragma unroll
            for (int r = 0; r < 4; r++)
                outV[(((size_t)b * 288 + (n0 >> 3) + (l16 >> 3)) * 256
                      + (ot0 + p) * 16 + quad * 4 + r) * 8 + (l16 & 7)]
                    = to_fp8(accV[p][r]);
    }
}

__global__ __launch_bounds__(256, 4)
void convqkv_kernel(const float* __restrict__ x, const float* __restrict__ token,
                    const bf16_t* __restrict__ WqL, const bf16_t* __restrict__ WkL,
                    const bf16_t* __restrict__ WvL,
                    u8* __restrict__ q8, u8* __restrict__ k8, u8* __restrict__ v8)
{
    __shared__ __align__(16) u8 smem[16 * (TC_ + 8) * 2 + 256];  // 16.9 KB (max of both paths)
    const int NB1 = B_ * HW_ / 16;   // 1152
    if ((int)blockIdx.x < NB1)
        conv_body<C_,  false, false>(x,     WqL, nullptr, q8, nullptr, blockIdx.x, smem);
    else
        conv_body<TC_, true,  true >(token, WkL, WvL,     k8, v8, blockIdx.x - NB1, smem);
    // (bid-1152)&7 == bid&7 since 1152 % 8 == 0 -> XCD affinity preserved.
}

// ---------------------------------------------------------------------------
// ROUND 12 attention: JS=1 + fused epilogue.  Grid 288 (b=bid&7, mt=bid>>3);
// each wave owns 16 q-rows and walks ALL 72 j-tiles (depth-2 prefetch, 3
// bufs, counted vmcnt(4), conflict-free layouts -- the r7 per-tile code,
// conflicts==0 verified).  Softmax denominator is complete in-wave, so
// out = x + alpha*O/l is written directly: epilogue kernel, Opart, lpart
// (and their ~56 MB of HBM traffic + one launch gap) are deleted.
// ---------------------------------------------------------------------------
__global__ __launch_bounds__(256, 3)
void attn_final_kernel(const u8* __restrict__ q8, const u8* __restrict__ k8,
                       const u8* __restrict__ v8, const float* __restrict__ x,
                       const float* __restrict__ alphaPtr, float* __restrict__ out)
{
    const int bid = blockIdx.x;
    const int b   = bid & 7;
    const int mt  = bid >> 3;
    const int wv   = threadIdx.x >> 6;
    const int lane = threadIdx.x & 63;
    const int quad = lane >> 4;
    const int l16  = lane & 15;
    const int row0 = mt * 64 + wv * 16;
    const int NT = HW_ / 32;   // 72 tiles

    const u8* qb = q8 + (size_t)b * HW_ * C_;
    const u8* kb = k8 + (size_t)b * 32 * HW_ * 8;    // k8' batch base
    const u8* vb = v8 + (size_t)b * 288 * 256 * 8;   // v8' batch base

    __shared__ u8 Kbuf[3][8192];
    __shared__ u8 Vbuf[3][8192];
    __shared__ float lsb[4][16];

    i64 aq[8];
    {
        const u8* r0 = qb + (size_t)(row0 + l16) * C_ + quad * 8;
#pragma unroll
        for (int t = 0; t < 8; t++) aq[t] = *(const i64*)(r0 + t * 32);
    }

    f32x4 O[16];
#pragma unroll
    for (int i = 0; i < 16; i++) O[i] = (f32x4){0.f, 0.f, 0.f, 0.f};
    float lsum = 0.f;

    // staging lane decomposition
    const int sQuad = (lane >> 3) & 3;   // col-chunk within t-block
    const int sRow2 = (lane & 7) * 2;    // row-pair base
    const int sHi   = lane >> 5;         // K: +16 rows | V: ct parity

#define STAGE(bufi, j0g)                                                       \
    {                                                                          \
        _Pragma("unroll")                                                      \
        for (int p = 0; p < 2; p++) {                                          \
            int i = wv * 2 + p;                                                \
            g2l16(kb + ((size_t)(i * 4 + sQuad) * HW_                          \
                        + (j0g) + sRow2 + sHi * 16) * 8,                       \
                  &Kbuf[bufi][i * 1024]);                                      \
        }                                                                      \
        _Pragma("unroll")                                                      \
        for (int p = 0; p < 2; p++) {                                          \
            int i = wv * 2 + p;                                                \
            g2l16(vb + (((size_t)((j0g) >> 3) + sQuad) * 256                   \
                        + (2 * i + sHi) * 16 + sRow2) * 8,                     \
                  &Vbuf[bufi][i * 1024]);                                      \
        }                                                                      \
    }

    STAGE(0, 0)
    STAGE(1, 32)

    const int roff = quad * 128 + l16 * 8;   // conflict-free fragment offset

    for (int tt = 0; tt < NT; tt++) {
        if (tt + 1 < NT) {
            asm volatile("s_waitcnt vmcnt(4)" ::: "memory");
        } else {
            asm volatile("s_waitcnt vmcnt(0)" ::: "memory");
        }
        __builtin_amdgcn_s_barrier();   // tile tt ready; buf[(tt+2)%3] free
        if (tt + 2 < NT)
            STAGE((tt + 2) % 3, (tt + 2) * 32)
        __builtin_amdgcn_sched_barrier(0);

        const u8* Kb = Kbuf[tt % 3];
        const u8* Vb = Vbuf[tt % 3];

        // S^T = K . Q^T : lane (l16,quad) accumulates S[qrow=l16][j=quad*4+r]
        f32x4 s00 = (f32x4){0.f,0.f,0.f,0.f}, s01 = (f32x4){0.f,0.f,0.f,0.f};
        __builtin_amdgcn_s_setprio(1);
#pragma unroll
        for (int t = 0; t < 8; t++) {
            i64 bk0 = *(const i64*)(Kb + t * 1024 + roff);
            i64 bk1 = *(const i64*)(Kb + t * 1024 + roff + 512);
            s00 = __builtin_amdgcn_mfma_f32_16x16x32_fp8_fp8(bk0, aq[t], s00, 0, 0, 0);
            s01 = __builtin_amdgcn_mfma_f32_16x16x32_fp8_fp8(bk1, aq[t], s01, 0, 0, 0);
        }
        __builtin_amdgcn_s_setprio(0);

        // exp + fp8 pack, all for q-row l16
        float pA0 = __expf(s00[0] * 0.0625f), pA1 = __expf(s00[1] * 0.0625f);
        float pA2 = __expf(s00[2] * 0.0625f), pA3 = __expf(s00[3] * 0.0625f);
        float pB0 = __expf(s01[0] * 0.0625f), pB1 = __expf(s01[1] * 0.0625f);
        float pB2 = __expf(s01[2] * 0.0625f), pB3 = __expf(s01[3] * 0.0625f);
        lsum += (pA0 + pA1 + pA2 + pA3) + (pB0 + pB1 + pB2 + pB3);

        u32 A  = __builtin_amdgcn_cvt_pk_fp8_f32(pA0, pA1, 0, false);
        A      = __builtin_amdgcn_cvt_pk_fp8_f32(pA2, pA3, A, true);
        u32 Bw = __builtin_amdgcn_cvt_pk_fp8_f32(pB0, pB1, 0, false);
        Bw     = __builtin_amdgcn_cvt_pk_fp8_f32(pB2, pB3, Bw, true);

        // in-register transpose to PV A-fragment (j = quad*8 .. quad*8+7)
        asm volatile("v_permlane32_swap_b32 %0, %1" : "+v"(A), "+v"(Bw));
        asm volatile("v_permlane16_swap_b32 %0, %1" : "+v"(A), "+v"(Bw));
        i64 ap0 = ((i64)(u32)Bw << 32) | (i64)A;

        __builtin_amdgcn_s_setprio(1);
#pragma unroll
        for (int ct = 0; ct < 16; ct++) {
            i64 bv = *(const i64*)(Vb + ct * 512 + roff);
            O[ct] = __builtin_amdgcn_mfma_f32_16x16x32_fp8_fp8(ap0, bv, O[ct], 0, 0, 0);
        }
        __builtin_amdgcn_s_setprio(0);
    }

    // full row sum (all j in-block now): combine the 4 quads of row l16
    lsum += __shfl_xor(lsum, 16);
    lsum += __shfl_xor(lsum, 32);
    if (quad == 0) lsb[wv][l16] = lsum;
    __syncthreads();

    // ---- fused epilogue: out = x + alpha * O / l ----
    const float a = *alphaPtr;
    float inv[4];
#pragma unroll
    for (int r = 0; r < 4; r++) inv[r] = a / lsb[wv][quad * 4 + r];

    const float* xb = x   + (size_t)b * C_ * HW_;
    float*       ob = out + (size_t)b * C_ * HW_;
#pragma unroll
    for (int ct = 0; ct < 16; ct++) {
        int c = ct * 16 + l16;
        f32x4 xv = *(const f32x4*)(xb + (size_t)c * HW_ + row0 + quad * 4);
        f32x4 rv;
#pragma unroll
        for (int r = 0; r < 4; r++) rv[r] = xv[r] + O[ct][r] * inv[r];
        *(f32x4*)(ob + (size_t)c * HW_ + row0 + quad * 4) = rv;
    }
#undef STAGE
}

// ---------------------------------------------------------------------------
extern "C" void kernel_launch(void* const* d_in, const int* in_sizes, int n_in,
                              void* d_out, int out_size, void* d_ws, size_t ws_size,
                              hipStream_t stream)
{
    (void)in_sizes; (void)n_in; (void)out_size; (void)ws_size;
    const float* x     = (const float*)d_in[0];
    const float* token = (const float*)d_in[1];
    const float* Wq    = (const float*)d_in[2];
    const float* Wk    = (const float*)d_in[3];
    const float* Wv    = (const float*)d_in[4];
    const float* alpha = (const float*)d_in[5];
    float* out = (float*)d_out;

    const size_t S = (size_t)B_ * HW_ * C_;   // 4,718,592 elements

    char* ws = (char*)d_ws;
    bf16_t* WqL = (bf16_t*)(ws + 6 * S);       // frag-major, 128 KB
    bf16_t* WkL = WqL + (size_t)C_ * C_;       // frag-major, 256 KB
    bf16_t* WvL = WkL + (size_t)C_ * TC_;      // frag-major, 256 KB
    u8*     q8  = (u8*)(ws + 7 * S);           // fp8 [b][n][C]
    u8*     k8  = (u8*)(ws + 8 * S);           // fp8 k8' [b][cc][j][8]
    u8*     v8  = (u8*)(ws + 9 * S);           // fp8 v8' [b][jc][c][8]

    wfrag_kernel<<<dim3(160), dim3(256), 0, stream>>>(Wq, Wk, Wv, WqL, WkL, WvL);
    convqkv_kernel<<<dim3(2 * B_ * HW_ / 16), dim3(256), 0, stream>>>(x, token, WqL, WkL, WvL, q8, k8, v8);
    attn_final_kernel<<<dim3(B_ * (HW_ / 64)), dim3(256), 0, stream>>>(q8, k8, v8, x, alpha, out);
}

// Round 13
// 211.920 us; speedup vs baseline: 1.1003x; 1.1003x over previous
//
#include <hip/hip_runtime.h>

#define B_   8
#define C_   256
#define TC_  512
#define HW_  2304   // 48*48
#define EPS_ 1e-6f

typedef __bf16 bf16_t;
typedef __bf16 bf16x8 __attribute__((ext_vector_type(8)));
typedef __bf16 bf16x4_t __attribute__((ext_vector_type(4)));
typedef float  f32x4 __attribute__((ext_vector_type(4)));
typedef unsigned int  u32;
typedef long long     i64;
typedef unsigned char u8;

// async 16B global->LDS; lds dest is wave-uniform base (lane i -> base+16i)
__device__ __forceinline__ void g2l16(const void* g, void* l) {
    __builtin_amdgcn_global_load_lds(
        (const __attribute__((address_space(1))) unsigned int*)g,
        (__attribute__((address_space(3))) unsigned int*)l, 16, 0, 0);
}

__device__ __forceinline__ u8 to_fp8(float v) {
    return (u8)(__builtin_amdgcn_cvt_pk_fp8_f32(v, v, 0, false) & 0xff);
}

// ---------------------------------------------------------------------------
// W -> fragment-major bf16 (unchanged).
// ---------------------------------------------------------------------------
__global__ __launch_bounds__(256)
void wfrag_kernel(const float* __restrict__ wq, const float* __restrict__ wk,
                  const float* __restrict__ wv,
                  bf16_t* __restrict__ oq, bf16_t* __restrict__ ok,
                  bf16_t* __restrict__ ov)
{
    const int fid = blockIdx.x * 4 + (threadIdx.x >> 6);   // 0..639
    const int lane = threadIdx.x & 63;
    const int l16 = lane & 15, quad = lane >> 4;

    const float* src; bf16_t* dst; int cin, f;
    if (fid < 128)      { src = wq; dst = oq; cin = C_;  f = fid; }
    else if (fid < 384) { src = wk; dst = ok; cin = TC_; f = fid - 128; }
    else                { src = wv; dst = ov; cin = TC_; f = fid - 384; }
    const int nks = cin / 32;
    const int ot = f / nks, ks = f % nks;

    const float* s = src + (size_t)(ot * 16 + l16) * cin + ks * 32 + quad * 8;
    float4 a = *(const float4*)(s);
    float4 b = *(const float4*)(s + 4);
    bf16x8 o;
    o[0] = (__bf16)a.x; o[1] = (__bf16)a.y; o[2] = (__bf16)a.z; o[3] = (__bf16)a.w;
    o[4] = (__bf16)b.x; o[5] = (__bf16)b.y; o[6] = (__bf16)b.z; o[7] = (__bf16)b.w;
    *(bf16x8*)(dst + (size_t)f * 512 + lane * 8) = o;
}

// ---------------------------------------------------------------------------
// ROUND 13: merged conv (r12 body, proven) kept; attn reverted to the r10
// JS=4 split (61 us proven, occupancy 22% -- r12's JS=1 grid of 288 blocks
// under-filled the machine: 11.7% occupancy, attn 91 us).  4 launches total.
// With attn at 61 us, any conv dispatch >= 62 us MUST surface in top-5 ->
// direct conv measurement either way.
//   KFMT=0: q8  [b][n][C]
//   KFMT=1: k8' [b][cchunk=o/8][j=n][8 bytes]
//   DO_V :  v8' [b][jchunk=n/8][c=o][8 bytes]
// ---------------------------------------------------------------------------
template<int CIN, bool DO_V, bool KFMT>
__device__ __forceinline__ void conv_body(const float* __restrict__ X,
                                          const bf16_t* __restrict__ Wa,
                                          const bf16_t* __restrict__ Wvp,
                                          u8* __restrict__ outA, u8* __restrict__ outV,
                                          int bid, u8* smem)
{
    const int b  = bid & 7;
    const int n0 = (bid >> 3) * 16;
    const int tid = threadIdx.x;
    const int wv = tid >> 6;
    const int lane = tid & 63;
    const int quad = lane >> 4, l16 = lane & 15;
    const int NKS = CIN / 32;

    bf16_t (*T)[CIN + 8] = (bf16_t (*)[CIN + 8])smem;
    float (*ssp)[16] = (float (*)[16])(smem + (size_t)16 * (CIN + 8) * 2);

    // ---- stage: fp32 [c][n] -> bf16 T[n][c] ----
    {
        const float* Xb = X + (size_t)b * CIN * HW_ + n0;
        const int cl = tid >> 2;          // 0..63
        const int n4 = (tid & 3) * 4;     // 0,4,8,12
#pragma unroll
        for (int cp = 0; cp < CIN; cp += 64) {
            float4 v = *(const float4*)(Xb + (size_t)(cp + cl) * HW_ + n4);
            T[n4 + 0][cp + cl] = (__bf16)v.x;
            T[n4 + 1][cp + cl] = (__bf16)v.y;
            T[n4 + 2][cp + cl] = (__bf16)v.z;
            T[n4 + 3][cp + cl] = (__bf16)v.w;
        }
    }
    __syncthreads();

    // ---- all 16 px rows into registers ----
    bf16x8 af[CIN / 32];
#pragma unroll
    for (int ks = 0; ks < CIN / 32; ks++)
        af[ks] = *(const bf16x8*)(&T[l16][ks * 32 + quad * 8]);

    const int ot0 = wv * 4;

    // ---- K-GEMM ----
    f32x4 accK[4];
#pragma unroll
    for (int p = 0; p < 4; p++) accK[p] = (f32x4){0.f, 0.f, 0.f, 0.f};
    {
        const bf16_t* wbase = Wa + ((size_t)ot0 * NKS) * 512 + lane * 8;
#pragma unroll
        for (int ks = 0; ks < CIN / 32; ks++)
#pragma unroll
            for (int p = 0; p < 4; p++) {
                bf16x8 bw = *(const bf16x8*)(wbase + (size_t)(p * NKS + ks) * 512);
                accK[p] = __builtin_amdgcn_mfma_f32_16x16x32_bf16(af[ks], bw, accK[p], 0, 0, 0);
            }
    }

    // ---- per-wave partial sum of squares over this wave's 64 o ----
    {
        float ssr[4];
#pragma unroll
        for (int r = 0; r < 4; r++) {
            float ss = accK[0][r] * accK[0][r] + accK[1][r] * accK[1][r]
                     + accK[2][r] * accK[2][r] + accK[3][r] * accK[3][r];
            ss += __shfl_xor(ss, 1);
            ss += __shfl_xor(ss, 2);
            ss += __shfl_xor(ss, 4);
            ss += __shfl_xor(ss, 8);
            ssr[r] = ss;
        }
        if (l16 == 0) {
#pragma unroll
            for (int r = 0; r < 4; r++) ssp[wv][quad * 4 + r] = ssr[r];
        }
    }

    // ---- V-GEMM (hides the ssp barrier) ----
    f32x4 accV[4];
    if (DO_V) {
#pragma unroll
        for (int p = 0; p < 4; p++) accV[p] = (f32x4){0.f, 0.f, 0.f, 0.f};
        const bf16_t* wbase = Wvp + ((size_t)ot0 * NKS) * 512 + lane * 8;
#pragma unroll
        for (int ks = 0; ks < CIN / 32; ks++)
#pragma unroll
            for (int p = 0; p < 4; p++) {
                bf16x8 aw = *(const bf16x8*)(wbase + (size_t)(p * NKS + ks) * 512);
                accV[p] = __builtin_amdgcn_mfma_f32_16x16x32_bf16(aw, af[ks], accV[p], 0, 0, 0);
            }
    }

    __syncthreads();

    // ---- combine norm partials, scale, write fp8 q/k ----
    float scale[4];
#pragma unroll
    for (int r = 0; r < 4; r++) {
        int px = quad * 4 + r;
        float s = ssp[0][px] + ssp[1][px] + ssp[2][px] + ssp[3][px];
        scale[r] = 1.0f / fmaxf(sqrtf(s), EPS_);
    }
    if (!KFMT) {
        // q8 [b][n][C]: row = px = quad*4+r, col = o = (ot0+p)*16 + l16
        u8* oa = outA + ((size_t)b * HW_ + n0 + quad * 4) * C_ + l16;
#pragma unroll
        for (int p = 0; p < 4; p++)
#pragma unroll
            for (int r = 0; r < 4; r++)
                oa[(size_t)r * C_ + (ot0 + p) * 16] = to_fp8(accK[p][r] * scale[r]);
    } else {
        // k8' [b][cc][j][8]: cc = o>>3 = (ot0+p)*2 + (l16>>3), byte = l16&7
        u8* oa = outA + (size_t)b * 32 * HW_ * 8;
#pragma unroll
        for (int p = 0; p < 4; p++)
#pragma unroll
            for (int r = 0; r < 4; r++)
                oa[(((size_t)((ot0 + p) * 2 + (l16 >> 3))) * HW_
                    + n0 + quad * 4 + r) * 8 + (l16 & 7)]
                    = to_fp8(accK[p][r] * scale[r]);
    }

    if (DO_V) {
        // v8' [b][jc][c][8]: jc = (n0+l16)>>3, c = o = (ot0+p)*16+quad*4+r
#pragma unroll
        for (int p = 0; p < 4; p++)
#pragma unroll
            for (int r = 0; r < 4; r++)
                outV[(((size_t)b * 288 + (n0 >> 3) + (l16 >> 3)) * 256
                      + (ot0 + p) * 16 + quad * 4 + r) * 8 + (l16 & 7)]
                    = to_fp8(accV[p][r]);
    }
}

__global__ __launch_bounds__(256, 4)
void convqkv_kernel(const float* __restrict__ x, const float* __restrict__ token,
                    const bf16_t* __restrict__ WqL, const bf16_t* __restrict__ WkL,
                    const bf16_t* __restrict__ WvL,
                    u8* __restrict__ q8, u8* __restrict__ k8, u8* __restrict__ v8)
{
    __shared__ __align__(16) u8 smem[16 * (TC_ + 8) * 2 + 256];  // 16.9 KB (max of both paths)
    const int NB1 = B_ * HW_ / 16;   // 1152
    if ((int)blockIdx.x < NB1)
        conv_body<C_,  false, false>(x,     WqL, nullptr, q8, nullptr, blockIdx.x, smem);
    else
        conv_body<TC_, true,  true >(token, WkL, WvL,     k8, v8, blockIdx.x - NB1, smem);
    // (bid-1152)&7 == bid&7 since 1152 % 8 == 0 -> XCD affinity preserved.
}

// ---------------------------------------------------------------------------
// Attention partials (r10 version, measured 61 us, conflicts == 0, JS=4):
// conflict-free K/V LDS layouts via k8'/v8' global formats; depth-2 prefetch
// (3 bufs), counted vmcnt(4), raw barrier, setprio.  JS=4 restores the
// 1152-block grid (3 blocks/CU resident, ~22% occupancy) that r12's JS=1
// lost (288 blocks -> 11.7% occupancy, attn 91 us).
// ---------------------------------------------------------------------------
__global__ __launch_bounds__(256, 3)
void attn_part_kernel(const u8* __restrict__ q8, const u8* __restrict__ k8,
                      const u8* __restrict__ v8,
                      bf16_t* __restrict__ Opart, float* __restrict__ lpart,
                      int tilesPerSplit, int JS)
{
    const int bid = blockIdx.x;
    const int b   = bid & 7;
    const int rr  = bid >> 3;
    const int js  = rr % JS;
    const int mt  = rr / JS;
    const int wv   = threadIdx.x >> 6;
    const int lane = threadIdx.x & 63;
    const int quad = lane >> 4;
    const int l16  = lane & 15;
    const int row0 = mt * 64 + wv * 16;
    const int jbase = js * tilesPerSplit * 32;

    const u8* qb = q8 + (size_t)b * HW_ * C_;
    const u8* kb = k8 + (size_t)b * 32 * HW_ * 8;    // k8' batch base
    const u8* vb = v8 + (size_t)b * 288 * 256 * 8;   // v8' batch base

    __shared__ u8 Kbuf[3][8192];
    __shared__ u8 Vbuf[3][8192];

    i64 aq[8];
    {
        const u8* r0 = qb + (size_t)(row0 + l16) * C_ + quad * 8;
#pragma unroll
        for (int t = 0; t < 8; t++) aq[t] = *(const i64*)(r0 + t * 32);
    }

    f32x4 O[16];
#pragma unroll
    for (int i = 0; i < 16; i++) O[i] = (f32x4){0.f, 0.f, 0.f, 0.f};
    float lsum = 0.f;

    // staging lane decomposition
    const int sQuad = (lane >> 3) & 3;   // col-chunk within t-block
    const int sRow2 = (lane & 7) * 2;    // row-pair base
    const int sHi   = lane >> 5;         // K: +16 rows | V: ct parity

#define STAGE(bufi, j0g)                                                       \
    {                                                                          \
        _Pragma("unroll")                                                      \
        for (int p = 0; p < 2; p++) {                                          \
            int i = wv * 2 + p;                                                \
            g2l16(kb + ((size_t)(i * 4 + sQuad) * HW_                          \
                        + (j0g) + sRow2 + sHi * 16) * 8,                       \
                  &Kbuf[bufi][i * 1024]);                                      \
        }                                                                      \
        _Pragma("unroll")                                                      \
        for (int p = 0; p < 2; p++) {                                          \
            int i = wv * 2 + p;                                                \
            g2l16(vb + (((size_t)((j0g) >> 3) + sQuad) * 256                   \
                        + (2 * i + sHi) * 16 + sRow2) * 8,                     \
                  &Vbuf[bufi][i * 1024]);                                      \
        }                                                                      \
    }

    STAGE(0, jbase)
    STAGE(1, jbase + 32)

    const int roff = quad * 128 + l16 * 8;   // conflict-free fragment offset

    for (int tt = 0; tt < tilesPerSplit; tt++) {
        if (tt + 1 < tilesPerSplit) {
            asm volatile("s_waitcnt vmcnt(4)" ::: "memory");
        } else {
            asm volatile("s_waitcnt vmcnt(0)" ::: "memory");
        }
        __builtin_amdgcn_s_barrier();   // tile tt ready; buf[(tt+2)%3] free
        if (tt + 2 < tilesPerSplit)
            STAGE((tt + 2) % 3, jbase + (tt + 2) * 32)
        __builtin_amdgcn_sched_barrier(0);

        const u8* Kb = Kbuf[tt % 3];
        const u8* Vb = Vbuf[tt % 3];

        // S^T = K . Q^T : lane (l16,quad) accumulates S[qrow=l16][j=quad*4+r]
        f32x4 s00 = (f32x4){0.f,0.f,0.f,0.f}, s01 = (f32x4){0.f,0.f,0.f,0.f};
        __builtin_amdgcn_s_setprio(1);
#pragma unroll
        for (int t = 0; t < 8; t++) {
            i64 bk0 = *(const i64*)(Kb + t * 1024 + roff);
            i64 bk1 = *(const i64*)(Kb + t * 1024 + roff + 512);
            s00 = __builtin_amdgcn_mfma_f32_16x16x32_fp8_fp8(bk0, aq[t], s00, 0, 0, 0);
            s01 = __builtin_amdgcn_mfma_f32_16x16x32_fp8_fp8(bk1, aq[t], s01, 0, 0, 0);
        }
        __builtin_amdgcn_s_setprio(0);

        // exp + fp8 pack, all for q-row l16
        float pA0 = __expf(s00[0] * 0.0625f), pA1 = __expf(s00[1] * 0.0625f);
        float pA2 = __expf(s00[2] * 0.0625f), pA3 = __expf(s00[3] * 0.0625f);
        float pB0 = __expf(s01[0] * 0.0625f), pB1 = __expf(s01[1] * 0.0625f);
        float pB2 = __expf(s01[2] * 0.0625f), pB3 = __expf(s01[3] * 0.0625f);
        lsum += (pA0 + pA1 + pA2 + pA3) + (pB0 + pB1 + pB2 + pB3);

        u32 A  = __builtin_amdgcn_cvt_pk_fp8_f32(pA0, pA1, 0, false);
        A      = __builtin_amdgcn_cvt_pk_fp8_f32(pA2, pA3, A, true);
        u32 Bw = __builtin_amdgcn_cvt_pk_fp8_f32(pB0, pB1, 0, false);
        Bw     = __builtin_amdgcn_cvt_pk_fp8_f32(pB2, pB3, Bw, true);

        // in-register transpose to PV A-fragment (j = quad*8 .. quad*8+7)
        asm volatile("v_permlane32_swap_b32 %0, %1" : "+v"(A), "+v"(Bw));
        asm volatile("v_permlane16_swap_b32 %0, %1" : "+v"(A), "+v"(Bw));
        i64 ap0 = ((i64)(u32)Bw << 32) | (i64)A;

        __builtin_amdgcn_s_setprio(1);
#pragma unroll
        for (int ct = 0; ct < 16; ct++) {
            i64 bv = *(const i64*)(Vb + ct * 512 + roff);
            O[ct] = __builtin_amdgcn_mfma_f32_16x16x32_fp8_fp8(ap0, bv, O[ct], 0, 0, 0);
        }
        __builtin_amdgcn_s_setprio(0);
    }

    // row sum: combine the 4 quads of column l16
    lsum += __shfl_xor(lsum, 16);
    lsum += __shfl_xor(lsum, 32);
    float* lp = lpart + (size_t)(js * B_ + b) * HW_;
    if (quad == 0) lp[row0 + l16] = lsum;

    bf16_t* op = Opart + (size_t)(js * B_ + b) * C_ * HW_;
#pragma unroll
    for (int ct = 0; ct < 16; ct++) {
        int c = ct * 16 + l16;
        bf16x4_t v0;
        v0[0] = (__bf16)O[ct][0]; v0[1] = (__bf16)O[ct][1];
        v0[2] = (__bf16)O[ct][2]; v0[3] = (__bf16)O[ct][3];
        *(bf16x4_t*)(op + (size_t)c * HW_ + row0 + quad * 4) = v0;
    }
#undef STAGE
}

// ---------------------------------------------------------------------------
// out[b][c][n] = x + alpha * (sum_js Opart) / (sum_js lpart[b][n])
// ---------------------------------------------------------------------------
__global__ __launch_bounds__(256)
void epilogue_kernel(const float* __restrict__ x, const bf16_t* __restrict__ Opart,
                     const float* __restrict__ lpart, const float* __restrict__ alphaPtr,
                     float* __restrict__ out, int JS)
{
    const float a = *alphaPtr;
    const size_t S = (size_t)B_ * C_ * HW_;
    size_t flat = ((size_t)blockIdx.x * 256 + threadIdx.x) * 4;
    int bc = (int)(flat / HW_);
    int n  = (int)(flat % HW_);
    int b  = bc >> 8;
    float4 xv = *(const float4*)(x + flat);
    float s0 = 0.f, s1 = 0.f, s2 = 0.f, s3 = 0.f;
    float l0 = 0.f, l1 = 0.f, l2 = 0.f, l3 = 0.f;
    for (int js = 0; js < JS; js++) {
        bf16x4_t ov = *(const bf16x4_t*)(Opart + (size_t)js * S + flat);
        s0 += (float)ov[0]; s1 += (float)ov[1];
        s2 += (float)ov[2]; s3 += (float)ov[3];
        float4 lv = *(const float4*)(lpart + (size_t)(js * B_ + b) * HW_ + n);
        l0 += lv.x; l1 += lv.y; l2 += lv.z; l3 += lv.w;
    }
    float4 r;
    r.x = xv.x + a * s0 / l0;
    r.y = xv.y + a * s1 / l1;
    r.z = xv.z + a * s2 / l2;
    r.w = xv.w + a * s3 / l3;
    *(float4*)(out + flat) = r;
}

// ---------------------------------------------------------------------------
extern "C" void kernel_launch(void* const* d_in, const int* in_sizes, int n_in,
                              void* d_out, int out_size, void* d_ws, size_t ws_size,
                              hipStream_t stream)
{
    (void)in_sizes; (void)n_in; (void)out_size;
    const float* x     = (const float*)d_in[0];
    const float* token = (const float*)d_in[1];
    const float* Wq    = (const float*)d_in[2];
    const float* Wk    = (const float*)d_in[3];
    const float* Wv    = (const float*)d_in[4];
    const float* alpha = (const float*)d_in[5];
    float* out = (float*)d_out;

    const size_t S = (size_t)B_ * HW_ * C_;   // 4,718,592 elements

    int JS = 4;
    for (;;) {
        size_t need = (12 + 2 * (size_t)JS) * S
                    + (size_t)JS * B_ * HW_ * 4 + (size_t)B_ * HW_ * 4;
        if (need <= ws_size || JS == 1) break;
        JS >>= 1;
    }
    const int tilesPerSplit = (HW_ / 32) / JS;  // 72/JS

    char* ws = (char*)d_ws;
    bf16_t* WqL   = (bf16_t*)(ws + 6 * S);       // frag-major, 128 KB
    bf16_t* WkL   = WqL + (size_t)C_ * C_;       // frag-major, 256 KB
    bf16_t* WvL   = WkL + (size_t)C_ * TC_;      // frag-major, 256 KB
    u8*     q8    = (u8*)(ws + 7 * S);           // fp8 [b][n][C]
    u8*     k8    = (u8*)(ws + 8 * S);           // fp8 k8' [b][cc][j][8]
    u8*     v8    = (u8*)(ws + 9 * S);           // fp8 v8' [b][jc][c][8]
    bf16_t* Opart = (bf16_t*)(ws + 12 * S);      // [js][b][c][n] bf16
    float*  lpart = (float*)(ws + (12 + 2 * (size_t)JS) * S);

    wfrag_kernel<<<dim3(160), dim3(256), 0, stream>>>(Wq, Wk, Wv, WqL, WkL, WvL);
    convqkv_kernel<<<dim3(2 * B_ * HW_ / 16), dim3(256), 0, stream>>>(x, token, WqL, WkL, WvL, q8, k8, v8);
    attn_part_kernel<<<dim3(JS * B_ * (HW_ / 64)), dim3(256), 0, stream>>>(q8, k8, v8, Opart, lpart, tilesPerSplit, JS);
    epilogue_kernel<<<dim3((int)(S / 1024)), dim3(256), 0, stream>>>(x, Opart, lpart, alpha, out, JS);
}